// Round 6
// baseline (362.259 us; speedup 1.0000x reference)
//
#include <hip/hip_runtime.h>

#define N_NODES 100000
#define FOUT 64

// partitioned-build constants
#define PSHIFT 9
#define PSIZE  512
#define NPART  ((N_NODES + PSIZE - 1) / PSIZE)   // 196
#define TILE   8192
#define SRCBITS 17
#define SRCMASK 0x1FFFF

#define SCAN_BLOCK 256
#define SCAN_ITEMS 8
#define SCAN_ELEMS (SCAN_BLOCK * SCAN_ITEMS)

typedef __attribute__((ext_vector_type(8))) short bf16x8;
typedef __attribute__((ext_vector_type(4))) float f32x4;
typedef __attribute__((ext_vector_type(2))) float f32x2;

// ---------------- bf16 helpers (manual, RNE) ----------------

static __device__ __forceinline__ float bf2f(unsigned short u) {
    union { unsigned int i; float f; } v;
    v.i = (unsigned int)u << 16;
    return v.f;
}
static __device__ __forceinline__ unsigned short f2bf(float f) {
    union { float f; unsigned int i; } v;
    v.f = f;
    unsigned int r = (v.i + 0x7fffu + ((v.i >> 16) & 1u)) >> 16;
    return (unsigned short)r;
}
static __device__ __forceinline__ unsigned int pk2(float x, float y) {
    return (unsigned int)f2bf(x) | ((unsigned int)f2bf(y) << 16);
}
// unpack one uint (2 bf16) -> f32x2 {low, high}
static __device__ __forceinline__ f32x2 up2v(unsigned int u) {
    union { unsigned int i; float f; } lo, hi;
    lo.i = u << 16;
    hi.i = u & 0xffff0000u;
    f32x2 r; r[0] = lo.f; r[1] = hi.f;
    return r;
}

template <typename T> static __device__ __forceinline__ void stf(T* p, float v);
template <> __device__ __forceinline__ void stf<float>(float* p, float v) { *p = v; }
template <> __device__ __forceinline__ void stf<unsigned short>(unsigned short* p, float v) { *p = f2bf(v); }

static __device__ __forceinline__ void st2(float* base, int idx, float2 v) {
    ((float2*)base)[idx] = v;
}
static __device__ __forceinline__ void st2(unsigned short* base, int idx, float2 v) {
    ((unsigned int*)base)[idx] = pk2(v.x, v.y);
}

// 8-col row store (fp32 or packed bf16) at row d, uint4-slot c4
static __device__ __forceinline__ void st8(float* base, int d, int c4,
                                           const float4& r0, const float4& r1) {
    ((float4*)base)[(size_t)d * 16 + 2 * c4]     = r0;
    ((float4*)base)[(size_t)d * 16 + 2 * c4 + 1] = r1;
}
static __device__ __forceinline__ void st8(unsigned short* base, int d, int c4,
                                           const float4& r0, const float4& r1) {
    uint4 u;
    u.x = pk2(r0.x, r0.y); u.y = pk2(r0.z, r0.w);
    u.z = pk2(r1.x, r1.y); u.w = pk2(r1.z, r1.w);
    ((uint4*)base)[(size_t)d * 8 + c4] = u;
}

// A-fragment load: 8 contiguous elems of one h row -> bf16x8
template <typename TIN> static __device__ __forceinline__ bf16x8 ldA(const TIN* p);
template <> __device__ __forceinline__ bf16x8 ldA<unsigned short>(const unsigned short* p) {
    return *(const bf16x8*)p;
}
template <> __device__ __forceinline__ bf16x8 ldA<float>(const float* p) {
    const f32x4* q = (const f32x4*)p;
    f32x4 lo = q[0], hi = q[1];
    bf16x8 a;
    a[0] = (short)f2bf(lo[0]); a[1] = (short)f2bf(lo[1]);
    a[2] = (short)f2bf(lo[2]); a[3] = (short)f2bf(lo[3]);
    a[4] = (short)f2bf(hi[0]); a[5] = (short)f2bf(hi[1]);
    a[6] = (short)f2bf(hi[2]); a[7] = (short)f2bf(hi[3]);
    return a;
}

// ---------------- setup: W->bf16 transposed, sentinel row, cursors, out_deg zero, ids ----------------

__global__ void k_setup(const float* __restrict__ W0, const float* __restrict__ W1,
                        const float* __restrict__ W2,
                        unsigned short* __restrict__ Wt0, unsigned short* __restrict__ Wt1,
                        unsigned short* __restrict__ Wt2, unsigned int* __restrict__ tzero,
                        int* __restrict__ dstCur, int capP, int* __restrict__ out_deg,
                        const int* __restrict__ ids, float* __restrict__ outid, int nid) {
    int i = blockIdx.x * blockDim.x + threadIdx.x;
    if (i < 128 * 64) {
        int k = i >> 6, n = i & 63;
        Wt0[n * 128 + k] = f2bf(W0[i]);
    }
    if (i < 64 * 64) {
        int k = i >> 6, n = i & 63;
        Wt1[n * 64 + k] = f2bf(W1[i]);
        Wt2[n * 64 + k] = f2bf(W2[i]);
    }
    if (i < 32) tzero[i] = 0u;   // 128 B zero row at t[N_NODES]
    if (i < NPART) dstCur[i] = i * capP;
    if (i < N_NODES) out_deg[i] = 0;
    if (i < nid) outid[i] = (float)ids[i];
}

// out-degree histogram: direct global atomics (100K L2-resident counters, avg 16 hits)
__global__ void k_odeg(const int* __restrict__ src, int* __restrict__ out_deg, int E) {
    int i = blockIdx.x * blockDim.x + threadIdx.x;
    int j = i * 4;
    if (j + 4 <= E) {
        int4 s = *(const int4*)&src[j];
        atomicAdd(&out_deg[s.x], 1);
        atomicAdd(&out_deg[s.y], 1);
        atomicAdd(&out_deg[s.z], 1);
        atomicAdd(&out_deg[s.w], 1);
    } else {
        for (; j < E; j++) atomicAdd(&out_deg[src[j]], 1);
    }
}

// ---------------- partitioned build (dst only, fixed-capacity partitions) ----------------

// per-tile LDS scatter into bin-contiguous staging; wave-per-bin coalesced flush.
__global__ void __launch_bounds__(1024) k_binscatter(
        const int* __restrict__ src, const int* __restrict__ dst,
        int* __restrict__ dstCur,
        unsigned int* __restrict__ dstStream, int E) {
    __shared__ unsigned int stageD[TILE];    // 32 KB
    __shared__ int dh[NPART];
    __shared__ int dLoc[NPART];
    __shared__ int dBase[NPART];
    __shared__ int dcur[NPART];
    __shared__ int sbuf[256];

    const int tid = threadIdx.x;
    const int base = blockIdx.x * TILE;
    const int end = min(base + TILE, E);

    if (tid < NPART) dh[tid] = 0;
    __syncthreads();

    for (int j = base + tid; j < end; j += 1024)
        atomicAdd(&dh[dst[j] >> PSHIFT], 1);
    __syncthreads();

    {
        int v = 0;
        if (tid < 256) { v = (tid < NPART) ? dh[tid] : 0; sbuf[tid] = v; }
        __syncthreads();
        for (int off = 1; off < 256; off <<= 1) {
            int x = 0;
            if (tid < 256 && tid >= off) x = sbuf[tid - off];
            __syncthreads();
            if (tid < 256) sbuf[tid] += x;
            __syncthreads();
        }
        if (tid < NPART) {
            int inc = sbuf[tid];
            dLoc[tid] = inc - v;
            dcur[tid] = inc - v;
            dBase[tid] = v ? atomicAdd(&dstCur[tid], v) : 0;
        }
        __syncthreads();
    }

    for (int j = base + tid; j < end; j += 1024) {
        int s = src[j], d = dst[j];
        int pd = atomicAdd(&dcur[d >> PSHIFT], 1);
        stageD[pd] = ((unsigned int)(d & (PSIZE - 1)) << SRCBITS) | (unsigned int)s;
    }
    __syncthreads();

    const int wv = tid >> 6;
    const int lane = tid & 63;
    for (int b = wv; b < NPART; b += 16) {
        const int cnt = dh[b];
        const int loc = dLoc[b];
        unsigned int* gd = dstStream + dBase[b];
        for (int i = lane; i < cnt; i += 64) gd[i] = stageD[loc + i];
    }
}

// per-dst-partition counting sort -> rowdeg{off,deg} + csr_src
__global__ void k_csr(const unsigned int* __restrict__ dstStream,
                      const int* __restrict__ dstCur, int capP,
                      int2* __restrict__ rowdeg, int* __restrict__ csr_src) {
    __shared__ int hist[PSIZE];
    __shared__ int part[PSIZE];
    const int tid = threadIdx.x;

    const int p = blockIdx.x;
    const int nodeBase = p << PSHIFT;
    const int nN = min(PSIZE, N_NODES - nodeBase);
    const int e0 = p * capP;
    const int e1 = dstCur[p];

    for (int i = tid; i < PSIZE; i += 512) hist[i] = 0;
    __syncthreads();
    for (int e = e0 + tid; e < e1; e += 512)
        atomicAdd(&hist[dstStream[e] >> SRCBITS], 1);
    __syncthreads();

    int c = hist[tid];
    part[tid] = c;
    __syncthreads();
    for (int off = 1; off < PSIZE; off <<= 1) {
        int v = (tid >= off) ? part[tid - off] : 0;
        __syncthreads();
        part[tid] += v;
        __syncthreads();
    }
    int run = part[tid] - c;            // exclusive
    hist[tid] = run;
    if (tid < nN) rowdeg[nodeBase + tid] = make_int2(e0 + run, c);
    __syncthreads();

    for (int e = e0 + tid; e < e1; e += 512) {
        unsigned int rec = dstStream[e];
        int d = rec >> SRCBITS;
        int sv = rec & SRCMASK;
        int pos = atomicAdd(&hist[d], 1);
        csr_src[e0 + pos] = sv;
    }
}

// ---------------- register-W MFMA gemm (no LDS, no barriers) ----------------
// t[r][:] = rsqrt(out_deg[r]+1) * (h[r][:] @ W)   -- out-norm commuted to output rows.
template <int FIN, typename TIN, typename TOUT>
__global__ void k_gemm_reg(const TIN* __restrict__ h, const int* __restrict__ out_deg,
                           const unsigned short* __restrict__ Wt, TOUT* __restrict__ t) {
    constexpr int NKC = FIN / 32;
    const int lane = threadIdx.x & 63;
    const int m = lane & 15;
    const int q = lane >> 4;
    const int wid = blockIdx.x * (blockDim.x >> 6) + (threadIdx.x >> 6);
    const int nw = (gridDim.x * blockDim.x) >> 6;
    const int nTiles = N_NODES / 16;    // 6250 exact

    bf16x8 bfrag[NKC][4];
#pragma unroll
    for (int kc = 0; kc < NKC; kc++)
#pragma unroll
        for (int nt = 0; nt < 4; nt++)
            bfrag[kc][nt] = *(const bf16x8*)&Wt[(nt * 16 + m) * FIN + kc * 32 + q * 8];

    for (int tile = wid; tile < nTiles; tile += nw) {
        const TIN* hrow = h + (size_t)(tile * 16 + m) * FIN + q * 8;
        f32x4 acc[4];
#pragma unroll
        for (int nt = 0; nt < 4; nt++) acc[nt] = (f32x4){0.f, 0.f, 0.f, 0.f};
#pragma unroll
        for (int kc = 0; kc < NKC; kc++) {
            bf16x8 a = ldA(hrow + kc * 32);
#pragma unroll
            for (int nt = 0; nt < 4; nt++)
                acc[nt] = __builtin_amdgcn_mfma_f32_16x16x32_bf16(a, bfrag[kc][nt], acc[nt], 0, 0, 0);
        }
        const int r0 = tile * 16 + q * 4;
        int4 dg = *(const int4*)&out_deg[r0];
        float s0 = rsqrtf((float)(dg.x + 1));
        float s1 = rsqrtf((float)(dg.y + 1));
        float s2 = rsqrtf((float)(dg.z + 1));
        float s3 = rsqrtf((float)(dg.w + 1));
#pragma unroll
        for (int nt = 0; nt < 4; nt++) {
            TOUT* tp = t + (size_t)r0 * FOUT + nt * 16 + m;
            stf(tp + 0 * FOUT, acc[nt][0] * s0);
            stf(tp + 1 * FOUT, acc[nt][1] * s1);
            stf(tp + 2 * FOUT, acc[nt][2] * s2);
            stf(tp + 3 * FOUT, acc[nt][3] * s3);
        }
    }
}

// ---------------- CSR SpMM: 8 slots x dwordx4, fine-grained masked tails ----------------
// 8 lanes x uint4 = one 128B bf16 row per edge slot; 8 slots/wave.
// Virtual edges vdeg = deg+1 (self at i==deg); i>deg gathers zero row t[N] (L1-hot).
// Tail chunk sizes {8,16,24,32} picked wave-uniformly -> avg slots ~21 for vdeg~17.

static __device__ __forceinline__ void accum8(f32x2* a, uint4 v) {
    a[0] += up2v(v.x);
    a[1] += up2v(v.y);
    a[2] += up2v(v.z);
    a[3] += up2v(v.w);
}

template <int G>   // G groups of 8 virtual edges, unmasked
static __device__ __forceinline__ void chunk_full8(
        const uint4* __restrict__ t4, const int* __restrict__ bk,
        int base, int sub, int c4, f32x2* acc) {
    int s[G];
#pragma unroll
    for (int u = 0; u < G; u++) s[u] = bk[base + sub + 8 * u];
    uint4 v[G];
#pragma unroll
    for (int u = 0; u < G; u++) v[u] = t4[(size_t)s[u] * 8 + c4];
#pragma unroll
    for (int u = 0; u < G; u++) accum8(acc, v[u]);
}

template <int G>   // G groups of 8 virtual edges, masked via sentinel row
static __device__ __forceinline__ void chunk_masked8(
        const uint4* __restrict__ t4, const int* __restrict__ bk,
        int base, int sub, int c4, int deg, int d, f32x2* acc) {
    int s[G];
#pragma unroll
    for (int u = 0; u < G; u++) {
        int i = base + sub + 8 * u;
        int sv = bk[i];                       // may read pad: value discarded below
        s[u] = (i < deg) ? sv : ((i == deg) ? d : N_NODES);
    }
    uint4 v[G];
#pragma unroll
    for (int u = 0; u < G; u++) v[u] = t4[(size_t)s[u] * 8 + c4];
#pragma unroll
    for (int u = 0; u < G; u++) accum8(acc, v[u]);
}

template <typename TOUT>
__global__ void k_spmm_b(const uint4* __restrict__ t4,   // bf16 rows, N+1 rows (row N = 0)
                         const int2* __restrict__ rowdeg, const int* __restrict__ csr_src,
                         const float* __restrict__ bias, TOUT* __restrict__ out) {
    const int wave = blockIdx.x * (blockDim.x >> 6) + (threadIdx.x >> 6);
    const int lane = threadIdx.x & 63;
    const int sub = lane >> 3;      // edge slot 0..7
    const int c4 = lane & 7;        // uint4 index within row (cols 8*c4 .. 8*c4+7)
    const int d = wave;
    const int2 rd = rowdeg[d];
    const int e0 = rd.x;
    const int deg = rd.y;
    const float inorm = rsqrtf((float)(deg + 1));
    const int* bk = csr_src + e0;
    const int vdeg = deg + 1;

    f32x2 a[4];
#pragma unroll
    for (int j = 0; j < 4; j++) a[j] = (f32x2){0.f, 0.f};

    int base = 0;
    while (vdeg - base > 32) {                 // rare (P[deg>31] ~ 2e-4)
        chunk_full8<4>(t4, bk, base, sub, c4, a);
        base += 32;
    }
    {   // wave-uniform tail ladder: {32,24,16,8} slots
        const int rem = vdeg - base;
        if (rem > 24)      chunk_masked8<4>(t4, bk, base, sub, c4, deg, d, a);
        else if (rem > 16) chunk_masked8<3>(t4, bk, base, sub, c4, deg, d, a);
        else if (rem > 8)  chunk_masked8<2>(t4, bk, base, sub, c4, deg, d, a);
        else               chunk_masked8<1>(t4, bk, base, sub, c4, deg, d, a);
    }

    // reduce across the 8 edge slots (lane bits 3,4,5)
#pragma unroll
    for (int off = 8; off < 64; off <<= 1) {
#pragma unroll
        for (int j = 0; j < 4; j++) {
            a[j][0] += __shfl_xor(a[j][0], off);
            a[j][1] += __shfl_xor(a[j][1], off);
        }
    }

    if (sub == 0) {
        const float4* b4 = (const float4*)bias;
        float4 bb0 = b4[2 * c4], bb1 = b4[2 * c4 + 1];
        float4 r0, r1;
        r0.x = inorm * a[0][0] + bb0.x;
        r0.y = inorm * a[0][1] + bb0.y;
        r0.z = inorm * a[1][0] + bb0.z;
        r0.w = inorm * a[1][1] + bb0.w;
        r1.x = inorm * a[2][0] + bb1.x;
        r1.y = inorm * a[2][1] + bb1.y;
        r1.z = inorm * a[3][0] + bb1.z;
        r1.w = inorm * a[3][1] + bb1.w;
        st8(out, d, c4, r0, r1);
    }
}

// ---------------- fallback path (fp32, atomic CSR build) ----------------

__global__ void k_init_fb(int* __restrict__ a, int* __restrict__ b,
                          const int* __restrict__ ids, float* __restrict__ outid,
                          int n, int nid) {
    int i = blockIdx.x * blockDim.x + threadIdx.x;
    if (i < n) { a[i] = 0; b[i] = 0; }
    if (i < nid) outid[i] = (float)ids[i];
}

__global__ void k_histo(const int* __restrict__ src, const int* __restrict__ dst,
                        int* __restrict__ out_deg, int* __restrict__ in_deg, int n) {
    int i = blockIdx.x * blockDim.x + threadIdx.x;
    if (i < n) {
        atomicAdd(&out_deg[src[i]], 1);
        atomicAdd(&in_deg[dst[i]], 1);
    }
}

__global__ void k_scan_partial(const int* __restrict__ deg, int* __restrict__ block_sums, int n) {
    __shared__ int red[SCAN_BLOCK];
    const int t = threadIdx.x;
    const int base = blockIdx.x * SCAN_ELEMS + t * SCAN_ITEMS;
    int s = 0;
#pragma unroll
    for (int k = 0; k < SCAN_ITEMS; k++) {
        int i = base + k;
        if (i < n) s += deg[i];
    }
    red[t] = s;
    __syncthreads();
    for (int off = SCAN_BLOCK / 2; off > 0; off >>= 1) {
        if (t < off) red[t] += red[t + off];
        __syncthreads();
    }
    if (t == 0) block_sums[blockIdx.x] = red[0];
}

__global__ void k_scan_blocks(int* __restrict__ block_sums, int nb) {
    __shared__ int sh[SCAN_BLOCK];
    const int t = threadIdx.x;
    sh[t] = (t < nb) ? block_sums[t] : 0;
    __syncthreads();
    for (int off = 1; off < SCAN_BLOCK; off <<= 1) {
        int v = (t >= off) ? sh[t - off] : 0;
        __syncthreads();
        sh[t] += v;
        __syncthreads();
    }
    if (t < nb) block_sums[t] = (t == 0) ? 0 : sh[t - 1];
}

__global__ void k_scan_write(const int* __restrict__ deg, const int* __restrict__ block_off,
                             int* __restrict__ row_off, int* __restrict__ cursor, int n) {
    __shared__ int sh[SCAN_BLOCK];
    const int t = threadIdx.x;
    const int base = blockIdx.x * SCAN_ELEMS + t * SCAN_ITEMS;
    int v[SCAN_ITEMS];
    int s = 0;
#pragma unroll
    for (int k = 0; k < SCAN_ITEMS; k++) {
        int i = base + k;
        v[k] = (i < n) ? deg[i] : 0;
        s += v[k];
    }
    sh[t] = s;
    __syncthreads();
    for (int off = 1; off < SCAN_BLOCK; off <<= 1) {
        int x = (t >= off) ? sh[t - off] : 0;
        __syncthreads();
        sh[t] += x;
        __syncthreads();
    }
    int run = block_off[blockIdx.x] + ((t == 0) ? 0 : sh[t - 1]);
#pragma unroll
    for (int k = 0; k < SCAN_ITEMS; k++) {
        int i = base + k;
        if (i < n) { row_off[i] = run; cursor[i] = run; run += v[k]; }
    }
    if (blockIdx.x == gridDim.x - 1 && t == SCAN_BLOCK - 1) {
        row_off[n] = block_off[blockIdx.x] + sh[SCAN_BLOCK - 1];
    }
}

__global__ void k_scatter(const int* __restrict__ src, const int* __restrict__ dst,
                          int* __restrict__ cursor, int* __restrict__ csr_src, int n) {
    int i = blockIdx.x * blockDim.x + threadIdx.x;
    if (i < n) {
        int d = dst[i];
        int pos = atomicAdd(&cursor[d], 1);
        csr_src[pos] = src[i];
    }
}

template <int FIN>
__global__ void k_gemm_fb(const float* __restrict__ h, const int* __restrict__ out_deg,
                          const float* __restrict__ W, float* __restrict__ t) {
    __shared__ float sh[32 * FIN];
    __shared__ float sno[32];
    const int tid = threadIdx.x;
    const int block0 = blockIdx.x * 32;

    if (tid < 32) sno[tid] = rsqrtf((float)(out_deg[block0 + tid] + 1));
    __syncthreads();

    for (int idx = tid; idx < 32 * FIN; idx += 256) {
        int r = idx / FIN;
        int c = idx % FIN;
        sh[idx] = h[(size_t)(block0 + r) * FIN + c] * sno[r];
    }
    __syncthreads();

    const int j2 = tid & 31;
    const int rg = tid >> 5;
    const float2* W2 = (const float2*)W;
    float2 a0 = {0.f, 0.f}, a1 = {0.f, 0.f}, a2 = {0.f, 0.f}, a3 = {0.f, 0.f};
#pragma unroll 4
    for (int k = 0; k < FIN; k++) {
        float2 w = W2[k * 32 + j2];
        float s0 = sh[(rg + 0)  * FIN + k];
        float s1 = sh[(rg + 8)  * FIN + k];
        float s2 = sh[(rg + 16) * FIN + k];
        float s3 = sh[(rg + 24) * FIN + k];
        a0.x += s0 * w.x; a0.y += s0 * w.y;
        a1.x += s1 * w.x; a1.y += s1 * w.y;
        a2.x += s2 * w.x; a2.y += s2 * w.y;
        a3.x += s3 * w.x; a3.y += s3 * w.y;
    }
    float* tp = t + (size_t)block0 * FOUT;
    st2(tp, (rg + 0)  * 32 + j2, a0);
    st2(tp, (rg + 8)  * 32 + j2, a1);
    st2(tp, (rg + 16) * 32 + j2, a2);
    st2(tp, (rg + 24) * 32 + j2, a3);
}

__global__ void k_spmm_c(const float* __restrict__ t, const int* __restrict__ row_off,
                         const int* __restrict__ csr_src, const float* __restrict__ bias,
                         float* __restrict__ out) {
    const int wave = blockIdx.x * (blockDim.x >> 6) + (threadIdx.x >> 6);
    const int lane = threadIdx.x & 63;
    const int d = wave;
    const int e0 = row_off[d];
    const int e1 = row_off[d + 1];
    const float inorm = rsqrtf((float)(e1 - e0 + 1));

    float a0 = t[(size_t)d * FOUT + lane];
    float a1 = 0.f, a2 = 0.f, a3 = 0.f, a4 = 0.f, a5 = 0.f, a6 = 0.f, a7 = 0.f;
    int e = e0;
    for (; e + 8 <= e1; e += 8) {
        int s0 = csr_src[e + 0], s1 = csr_src[e + 1], s2 = csr_src[e + 2], s3 = csr_src[e + 3];
        int s4 = csr_src[e + 4], s5 = csr_src[e + 5], s6 = csr_src[e + 6], s7 = csr_src[e + 7];
        a0 += t[(size_t)s0 * FOUT + lane];
        a1 += t[(size_t)s1 * FOUT + lane];
        a2 += t[(size_t)s2 * FOUT + lane];
        a3 += t[(size_t)s3 * FOUT + lane];
        a4 += t[(size_t)s4 * FOUT + lane];
        a5 += t[(size_t)s5 * FOUT + lane];
        a6 += t[(size_t)s6 * FOUT + lane];
        a7 += t[(size_t)s7 * FOUT + lane];
    }
    for (; e + 4 <= e1; e += 4) {
        int s0 = csr_src[e + 0], s1 = csr_src[e + 1], s2 = csr_src[e + 2], s3 = csr_src[e + 3];
        a0 += t[(size_t)s0 * FOUT + lane];
        a1 += t[(size_t)s1 * FOUT + lane];
        a2 += t[(size_t)s2 * FOUT + lane];
        a3 += t[(size_t)s3 * FOUT + lane];
    }
    for (; e < e1; e++) a0 += t[(size_t)csr_src[e] * FOUT + lane];

    float acc = ((a0 + a1) + (a2 + a3)) + ((a4 + a5) + (a6 + a7));
    out[(size_t)d * FOUT + lane] = inorm * acc + bias[lane];
}

// ---------------- launch ----------------

extern "C" void kernel_launch(void* const* d_in, const int* in_sizes, int n_in,
                              void* d_out, int out_size, void* d_ws, size_t ws_size,
                              hipStream_t stream) {
    const float* h   = (const float*)d_in[0];
    const int*   src = (const int*)d_in[1];
    const int*   dst = (const int*)d_in[2];
    const int*   ids = (const int*)d_in[3];
    const float* W0  = (const float*)d_in[4];
    const float* b0  = (const float*)d_in[5];
    const float* W1  = (const float*)d_in[6];
    const float* b1  = (const float*)d_in[7];
    const float* W2  = (const float*)d_in[8];
    const float* b2  = (const float*)d_in[9];
    const int N = N_NODES;
    const int E = in_sizes[1];

    size_t o = 0;
    auto alloc = [&](size_t nbytes) -> void* {
        void* p = (char*)d_ws + o;
        o += (nbytes + 255) & ~(size_t)255;
        return p;
    };

    float* outp = (float*)d_out;
    const int B = 256;
    const int spmmGrid = N / 4;            // 25000 blocks x 4 waves
    const int gemmGrid = (N / 16 + 3) / 4; // 6250 wave-tiles, 4 waves/block -> 1563

    // fixed partition capacity: mean + huge slack, rounded to 256
    const int capP = (((E / NPART) * 9) / 8 + 512 + 255) & ~255;
    const size_t streamEnt = (size_t)NPART * capP;

    const size_t needNew =
        ((streamEnt * 4 + 255) & ~(size_t)255) +           // dstStream
        ((streamEnt * 4 + 255) & ~(size_t)255) +           // csr_src
        (((size_t)N * 8 + 255) & ~(size_t)255) +           // rowdeg
        (((size_t)N * 4 + 255) & ~(size_t)255) +           // out_deg
        1024 +                                              // dstCur
        2 * (((size_t)(N + 1) * FOUT * 2 + 255) & ~(size_t)255) +  // t, hbuf
        64 * 1024 + 4096;

    if (ws_size >= needNew) {
        // ---------- single-pass partitioned build + register-W gemm + 16B-gather spmm ----------
        unsigned int*   dstStream = (unsigned int*)alloc(streamEnt * 4);
        int*            csr_src   = (int*)alloc(streamEnt * 4);
        int2*           rowdeg    = (int2*)alloc((size_t)N * 8);
        int*            out_deg   = (int*)alloc((size_t)N * 4);
        int*            dstCur    = (int*)alloc(1024);
        unsigned short* t         = (unsigned short*)alloc((size_t)(N + 1) * FOUT * 2);  // +1 zero row
        unsigned short* hbuf      = (unsigned short*)alloc((size_t)N * FOUT * 2);
        unsigned short* Wt0       = (unsigned short*)alloc(128 * 64 * 2);
        unsigned short* Wt1       = (unsigned short*)alloc(64 * 64 * 2);
        unsigned short* Wt2       = (unsigned short*)alloc(64 * 64 * 2);

        const int nTiles = (E + TILE - 1) / TILE;   // 196

        k_setup<<<(N + B - 1) / B, B, 0, stream>>>(W0, W1, W2, Wt0, Wt1, Wt2,
                                                   (unsigned int*)(t + (size_t)N * FOUT),
                                                   dstCur, capP, out_deg,
                                                   ids, outp + (size_t)N * FOUT, 1024);
        k_odeg<<<(E / 4 + B - 1) / B, B, 0, stream>>>(src, out_deg, E);
        k_binscatter<<<nTiles, 1024, 0, stream>>>(src, dst, dstCur, dstStream, E);
        k_csr<<<NPART, 512, 0, stream>>>(dstStream, dstCur, capP, rowdeg, csr_src);

        // layer 0: 128 -> 64 (fp32 in, bf16 out)
        k_gemm_reg<128, float, unsigned short><<<gemmGrid, B, 0, stream>>>(h, out_deg, Wt0, t);
        k_spmm_b<unsigned short><<<spmmGrid, B, 0, stream>>>((const uint4*)t, rowdeg, csr_src, b0, hbuf);
        // layer 1
        k_gemm_reg<64, unsigned short, unsigned short><<<gemmGrid, B, 0, stream>>>(hbuf, out_deg, Wt1, t);
        k_spmm_b<unsigned short><<<spmmGrid, B, 0, stream>>>((const uint4*)t, rowdeg, csr_src, b1, hbuf);
        // layer 2 (fp32 final out)
        k_gemm_reg<64, unsigned short, unsigned short><<<gemmGrid, B, 0, stream>>>(hbuf, out_deg, Wt2, t);
        k_spmm_b<float><<<spmmGrid, B, 0, stream>>>((const uint4*)t, rowdeg, csr_src, b2, outp);
    } else {
        // ---------- CSR fallback (fp32, atomic build) ----------
        int*   in_deg  = (int*)alloc((size_t)N * 4);
        int*   out_deg = (int*)alloc((size_t)N * 4);
        int*   row_off = (int*)alloc((size_t)(N + 1) * 4);
        int*   cursor  = (int*)alloc((size_t)N * 4);
        int*   csr_src = (int*)alloc((size_t)E * 4);
        float* t       = (float*)alloc((size_t)N * FOUT * 4);
        float* hbuf    = (float*)alloc((size_t)N * FOUT * 4);
        int*   bsums   = (int*)alloc((size_t)SCAN_BLOCK * 4);

        const int gN = (N + B - 1) / B;
        const int gE = (E + B - 1) / B;
        const int nScanBlocks = (N + SCAN_ELEMS - 1) / SCAN_ELEMS;

        k_init_fb<<<gN, B, 0, stream>>>(in_deg, out_deg, ids, outp + (size_t)N * FOUT, N, 1024);
        k_histo<<<gE, B, 0, stream>>>(src, dst, out_deg, in_deg, E);
        k_scan_partial<<<nScanBlocks, SCAN_BLOCK, 0, stream>>>(in_deg, bsums, N);
        k_scan_blocks<<<1, SCAN_BLOCK, 0, stream>>>(bsums, nScanBlocks);
        k_scan_write<<<nScanBlocks, SCAN_BLOCK, 0, stream>>>(in_deg, bsums, row_off, cursor, N);
        k_scatter<<<gE, B, 0, stream>>>(src, dst, cursor, csr_src, E);

        k_gemm_fb<128><<<N / 32, 256, 0, stream>>>(h, out_deg, W0, t);
        k_spmm_c<<<spmmGrid, 256, 0, stream>>>(t, row_off, csr_src, b0, hbuf);
        k_gemm_fb<64><<<N / 32, 256, 0, stream>>>(hbuf, out_deg, W1, t);
        k_spmm_c<<<spmmGrid, 256, 0, stream>>>(t, row_off, csr_src, b1, hbuf);
        k_gemm_fb<64><<<N / 32, 256, 0, stream>>>(hbuf, out_deg, W2, t);
        k_spmm_c<<<spmmGrid, 256, 0, stream>>>(t, row_off, csr_src, b2, outp);
    }
}

// Round 7
// 301.659 us; speedup vs baseline: 1.2009x; 1.2009x over previous
//
#include <hip/hip_runtime.h>

#define N_NODES 100000
#define FOUT 64

// partitioned-build constants
#define PSHIFT 9
#define PSIZE  512
#define NPART  ((N_NODES + PSIZE - 1) / PSIZE)   // 196
#define TILE   8192
#define SRCBITS 17
#define SRCMASK 0x1FFFF

#define SCAN_BLOCK 256
#define SCAN_ITEMS 8
#define SCAN_ELEMS (SCAN_BLOCK * SCAN_ITEMS)

typedef __attribute__((ext_vector_type(8))) short bf16x8;
typedef __attribute__((ext_vector_type(4))) float f32x4;
typedef __attribute__((ext_vector_type(2))) float f32x2;

// ---------------- bf16 helpers (manual, RNE) ----------------

static __device__ __forceinline__ float bf2f(unsigned short u) {
    union { unsigned int i; float f; } v;
    v.i = (unsigned int)u << 16;
    return v.f;
}
static __device__ __forceinline__ unsigned short f2bf(float f) {
    union { float f; unsigned int i; } v;
    v.f = f;
    unsigned int r = (v.i + 0x7fffu + ((v.i >> 16) & 1u)) >> 16;
    return (unsigned short)r;
}
static __device__ __forceinline__ unsigned int pk2(float x, float y) {
    return (unsigned int)f2bf(x) | ((unsigned int)f2bf(y) << 16);
}
// unpack one uint (2 bf16) -> f32x2 {low, high}
static __device__ __forceinline__ f32x2 up2v(unsigned int u) {
    union { unsigned int i; float f; } lo, hi;
    lo.i = u << 16;
    hi.i = u & 0xffff0000u;
    f32x2 r; r[0] = lo.f; r[1] = hi.f;
    return r;
}

template <typename T> static __device__ __forceinline__ void stf(T* p, float v);
template <> __device__ __forceinline__ void stf<float>(float* p, float v) { *p = v; }
template <> __device__ __forceinline__ void stf<unsigned short>(unsigned short* p, float v) { *p = f2bf(v); }

static __device__ __forceinline__ void st2(float* base, int idx, float2 v) {
    ((float2*)base)[idx] = v;
}
static __device__ __forceinline__ void st2(unsigned short* base, int idx, float2 v) {
    ((unsigned int*)base)[idx] = pk2(v.x, v.y);
}

// 8-col row store (fp32 or packed bf16) at row d, uint4-slot c4
static __device__ __forceinline__ void st8(float* base, int d, int c4,
                                           const float4& r0, const float4& r1) {
    ((float4*)base)[(size_t)d * 16 + 2 * c4]     = r0;
    ((float4*)base)[(size_t)d * 16 + 2 * c4 + 1] = r1;
}
static __device__ __forceinline__ void st8(unsigned short* base, int d, int c4,
                                           const float4& r0, const float4& r1) {
    uint4 u;
    u.x = pk2(r0.x, r0.y); u.y = pk2(r0.z, r0.w);
    u.z = pk2(r1.x, r1.y); u.w = pk2(r1.z, r1.w);
    ((uint4*)base)[(size_t)d * 8 + c4] = u;
}

// A-fragment load: 8 contiguous elems of one h row -> bf16x8
template <typename TIN> static __device__ __forceinline__ bf16x8 ldA(const TIN* p);
template <> __device__ __forceinline__ bf16x8 ldA<unsigned short>(const unsigned short* p) {
    return *(const bf16x8*)p;
}
template <> __device__ __forceinline__ bf16x8 ldA<float>(const float* p) {
    const f32x4* q = (const f32x4*)p;
    f32x4 lo = q[0], hi = q[1];
    bf16x8 a;
    a[0] = (short)f2bf(lo[0]); a[1] = (short)f2bf(lo[1]);
    a[2] = (short)f2bf(lo[2]); a[3] = (short)f2bf(lo[3]);
    a[4] = (short)f2bf(hi[0]); a[5] = (short)f2bf(hi[1]);
    a[6] = (short)f2bf(hi[2]); a[7] = (short)f2bf(hi[3]);
    return a;
}

// ---------------- setup: W->bf16 transposed, sentinel row, cursors, ids ----------------

__global__ void k_setup(const float* __restrict__ W0, const float* __restrict__ W1,
                        const float* __restrict__ W2,
                        unsigned short* __restrict__ Wt0, unsigned short* __restrict__ Wt1,
                        unsigned short* __restrict__ Wt2, unsigned int* __restrict__ tzero,
                        int* __restrict__ dstCur, int* __restrict__ srcCur, int capP,
                        const int* __restrict__ ids, float* __restrict__ outid, int nid) {
    int i = blockIdx.x * blockDim.x + threadIdx.x;
    if (i < 128 * 64) {
        int k = i >> 6, n = i & 63;
        Wt0[n * 128 + k] = f2bf(W0[i]);
    }
    if (i < 64 * 64) {
        int k = i >> 6, n = i & 63;
        Wt1[n * 64 + k] = f2bf(W1[i]);
        Wt2[n * 64 + k] = f2bf(W2[i]);
    }
    if (i < 32) tzero[i] = 0u;   // 128 B zero row at t[N_NODES]
    if (i < NPART) { dstCur[i] = i * capP; srcCur[i] = i * capP; }
    if (i < nid) outid[i] = (float)ids[i];
}

// ---------------- partitioned build (single pass, fixed-capacity partitions) ----------------

// per-tile LDS scatter into bin-contiguous staging; wave-per-bin coalesced flush.
// Global reservation straight off the partition cursors (pre-init'd to p*capP).
__global__ void __launch_bounds__(1024) k_binscatter(
        const int* __restrict__ src, const int* __restrict__ dst,
        int* __restrict__ dstCur, int* __restrict__ srcCur,
        unsigned int* __restrict__ dstStream,
        unsigned short* __restrict__ srcStream, int E) {
    __shared__ unsigned int   stageD[TILE];    // 32 KB
    __shared__ unsigned short stageS[TILE];    // 16 KB
    __shared__ int dh[NPART], sh2[NPART];
    __shared__ int dLoc[NPART], sLoc[NPART];
    __shared__ int dBase[NPART], sBase[NPART];
    __shared__ int dcur[NPART], scur[NPART];
    __shared__ int sbuf[256];

    const int tid = threadIdx.x;
    const int base = blockIdx.x * TILE;
    const int end = min(base + TILE, E);

    if (tid < NPART) { dh[tid] = 0; sh2[tid] = 0; }
    __syncthreads();

    for (int j = base + tid; j < end; j += 1024) {
        atomicAdd(&dh[dst[j] >> PSHIFT], 1);
        atomicAdd(&sh2[src[j] >> PSHIFT], 1);
    }
    __syncthreads();

    {
        int v = 0;
        if (tid < 256) { v = (tid < NPART) ? dh[tid] : 0; sbuf[tid] = v; }
        __syncthreads();
        for (int off = 1; off < 256; off <<= 1) {
            int x = 0;
            if (tid < 256 && tid >= off) x = sbuf[tid - off];
            __syncthreads();
            if (tid < 256) sbuf[tid] += x;
            __syncthreads();
        }
        if (tid < NPART) {
            int inc = sbuf[tid];
            dLoc[tid] = inc - v;
            dcur[tid] = inc - v;
            dBase[tid] = v ? atomicAdd(&dstCur[tid], v) : 0;
        }
        __syncthreads();
    }
    {
        int v = 0;
        if (tid < 256) { v = (tid < NPART) ? sh2[tid] : 0; sbuf[tid] = v; }
        __syncthreads();
        for (int off = 1; off < 256; off <<= 1) {
            int x = 0;
            if (tid < 256 && tid >= off) x = sbuf[tid - off];
            __syncthreads();
            if (tid < 256) sbuf[tid] += x;
            __syncthreads();
        }
        if (tid < NPART) {
            int inc = sbuf[tid];
            sLoc[tid] = inc - v;
            scur[tid] = inc - v;
            sBase[tid] = v ? atomicAdd(&srcCur[tid], v) : 0;
        }
        __syncthreads();
    }

    for (int j = base + tid; j < end; j += 1024) {
        int s = src[j], d = dst[j];
        int pd = atomicAdd(&dcur[d >> PSHIFT], 1);
        stageD[pd] = ((unsigned int)(d & (PSIZE - 1)) << SRCBITS) | (unsigned int)s;
        int ps = atomicAdd(&scur[s >> PSHIFT], 1);
        stageS[ps] = (unsigned short)(s & (PSIZE - 1));
    }
    __syncthreads();

    const int wv = tid >> 6;
    const int lane = tid & 63;
    for (int b = wv; b < NPART; b += 16) {
        const int cnt  = dh[b];
        const int loc  = dLoc[b];
        unsigned int* gd = dstStream + dBase[b];
        for (int i = lane; i < cnt; i += 64) gd[i] = stageD[loc + i];
        const int cnt2 = sh2[b];
        const int loc2 = sLoc[b];
        unsigned short* gs = srcStream + sBase[b];
        for (int i = lane; i < cnt2; i += 64) gs[i] = stageS[loc2 + i];
    }
}

// fused: blocks [0,NPART) counting-sort dst partitions -> rowdeg{off,deg} + csr_src;
//        blocks [NPART,2*NPART) histogram src partitions -> out_deg.
__global__ void k_csr_odeg(const unsigned int* __restrict__ dstStream,
                           const unsigned short* __restrict__ srcStream,
                           const int* __restrict__ dstCur, const int* __restrict__ srcCur,
                           int capP,
                           int2* __restrict__ rowdeg, int* __restrict__ csr_src,
                           int* __restrict__ out_deg) {
    __shared__ int hist[PSIZE];
    __shared__ int part[PSIZE];
    const int tid = threadIdx.x;

    if (blockIdx.x < NPART) {
        const int p = blockIdx.x;
        const int nodeBase = p << PSHIFT;
        const int nN = min(PSIZE, N_NODES - nodeBase);
        const int e0 = p * capP;
        const int e1 = dstCur[p];

        for (int i = tid; i < PSIZE; i += 512) hist[i] = 0;
        __syncthreads();
        for (int e = e0 + tid; e < e1; e += 512)
            atomicAdd(&hist[dstStream[e] >> SRCBITS], 1);
        __syncthreads();

        int c = hist[tid];
        part[tid] = c;
        __syncthreads();
        for (int off = 1; off < PSIZE; off <<= 1) {
            int v = (tid >= off) ? part[tid - off] : 0;
            __syncthreads();
            part[tid] += v;
            __syncthreads();
        }
        int run = part[tid] - c;            // exclusive
        hist[tid] = run;
        if (tid < nN) rowdeg[nodeBase + tid] = make_int2(e0 + run, c);
        __syncthreads();

        for (int e = e0 + tid; e < e1; e += 512) {
            unsigned int rec = dstStream[e];
            int d = rec >> SRCBITS;
            int sv = rec & SRCMASK;
            int pos = atomicAdd(&hist[d], 1);
            csr_src[e0 + pos] = sv;
        }
    } else {
        const int p = blockIdx.x - NPART;
        const int nodeBase = p << PSHIFT;
        const int nN = min(PSIZE, N_NODES - nodeBase);
        const int e0 = p * capP;
        const int e1 = srcCur[p];

        for (int i = tid; i < PSIZE; i += 512) hist[i] = 0;
        __syncthreads();
        for (int e = e0 + tid; e < e1; e += 512)
            atomicAdd(&hist[srcStream[e]], 1);
        __syncthreads();
        if (tid < nN) out_deg[nodeBase + tid] = hist[tid];
    }
}

// ---------------- register-W MFMA gemm (no LDS, no barriers) ----------------
// t[r][:] = rsqrt(out_deg[r]+1) * (h[r][:] @ W)   -- out-norm commuted to output rows.
template <int FIN, typename TIN, typename TOUT>
__global__ void k_gemm_reg(const TIN* __restrict__ h, const int* __restrict__ out_deg,
                           const unsigned short* __restrict__ Wt, TOUT* __restrict__ t) {
    constexpr int NKC = FIN / 32;
    const int lane = threadIdx.x & 63;
    const int m = lane & 15;
    const int q = lane >> 4;
    const int wid = blockIdx.x * (blockDim.x >> 6) + (threadIdx.x >> 6);
    const int nw = (gridDim.x * blockDim.x) >> 6;
    const int nTiles = N_NODES / 16;    // 6250 exact

    bf16x8 bfrag[NKC][4];
#pragma unroll
    for (int kc = 0; kc < NKC; kc++)
#pragma unroll
        for (int nt = 0; nt < 4; nt++)
            bfrag[kc][nt] = *(const bf16x8*)&Wt[(nt * 16 + m) * FIN + kc * 32 + q * 8];

    for (int tile = wid; tile < nTiles; tile += nw) {
        const TIN* hrow = h + (size_t)(tile * 16 + m) * FIN + q * 8;
        f32x4 acc[4];
#pragma unroll
        for (int nt = 0; nt < 4; nt++) acc[nt] = (f32x4){0.f, 0.f, 0.f, 0.f};
#pragma unroll
        for (int kc = 0; kc < NKC; kc++) {
            bf16x8 a = ldA(hrow + kc * 32);
#pragma unroll
            for (int nt = 0; nt < 4; nt++)
                acc[nt] = __builtin_amdgcn_mfma_f32_16x16x32_bf16(a, bfrag[kc][nt], acc[nt], 0, 0, 0);
        }
        const int r0 = tile * 16 + q * 4;
        int4 dg = *(const int4*)&out_deg[r0];
        float s0 = rsqrtf((float)(dg.x + 1));
        float s1 = rsqrtf((float)(dg.y + 1));
        float s2 = rsqrtf((float)(dg.z + 1));
        float s3 = rsqrtf((float)(dg.w + 1));
#pragma unroll
        for (int nt = 0; nt < 4; nt++) {
            TOUT* tp = t + (size_t)r0 * FOUT + nt * 16 + m;
            stf(tp + 0 * FOUT, acc[nt][0] * s0);
            stf(tp + 1 * FOUT, acc[nt][1] * s1);
            stf(tp + 2 * FOUT, acc[nt][2] * s2);
            stf(tp + 3 * FOUT, acc[nt][3] * s3);
        }
    }
}

// ---------------- CSR SpMM: 8 slots x dwordx4, fine-grained masked tails ----------------
// 8 lanes x uint4 = one 128B bf16 row per edge slot; 8 slots/wave.
// Virtual edges vdeg = deg+1 (self at i==deg); i>deg gathers zero row t[N] (L1-hot).
// Tail chunk sizes {8,16,24,32} picked wave-uniformly -> avg slots ~21 for vdeg~17.

static __device__ __forceinline__ void accum8(f32x2* a, uint4 v) {
    a[0] += up2v(v.x);
    a[1] += up2v(v.y);
    a[2] += up2v(v.z);
    a[3] += up2v(v.w);
}

template <int G>   // G groups of 8 virtual edges, unmasked
static __device__ __forceinline__ void chunk_full8(
        const uint4* __restrict__ t4, const int* __restrict__ bk,
        int base, int sub, int c4, f32x2* acc) {
    int s[G];
#pragma unroll
    for (int u = 0; u < G; u++) s[u] = bk[base + sub + 8 * u];
    uint4 v[G];
#pragma unroll
    for (int u = 0; u < G; u++) v[u] = t4[(size_t)s[u] * 8 + c4];
#pragma unroll
    for (int u = 0; u < G; u++) accum8(acc, v[u]);
}

template <int G>   // G groups of 8 virtual edges, masked via sentinel row
static __device__ __forceinline__ void chunk_masked8(
        const uint4* __restrict__ t4, const int* __restrict__ bk,
        int base, int sub, int c4, int deg, int d, f32x2* acc) {
    int s[G];
#pragma unroll
    for (int u = 0; u < G; u++) {
        int i = base + sub + 8 * u;
        int sv = bk[i];                       // may read pad: value discarded below
        s[u] = (i < deg) ? sv : ((i == deg) ? d : N_NODES);
    }
    uint4 v[G];
#pragma unroll
    for (int u = 0; u < G; u++) v[u] = t4[(size_t)s[u] * 8 + c4];
#pragma unroll
    for (int u = 0; u < G; u++) accum8(acc, v[u]);
}

template <typename TOUT>
__global__ void k_spmm_b(const uint4* __restrict__ t4,   // bf16 rows, N+1 rows (row N = 0)
                         const int2* __restrict__ rowdeg, const int* __restrict__ csr_src,
                         const float* __restrict__ bias, TOUT* __restrict__ out) {
    const int wave = blockIdx.x * (blockDim.x >> 6) + (threadIdx.x >> 6);
    const int lane = threadIdx.x & 63;
    const int sub = lane >> 3;      // edge slot 0..7
    const int c4 = lane & 7;        // uint4 index within row (cols 8*c4 .. 8*c4+7)
    const int d = wave;
    const int2 rd = rowdeg[d];
    const int e0 = rd.x;
    const int deg = rd.y;
    const float inorm = rsqrtf((float)(deg + 1));
    const int* bk = csr_src + e0;
    const int vdeg = deg + 1;

    f32x2 a[4];
#pragma unroll
    for (int j = 0; j < 4; j++) a[j] = (f32x2){0.f, 0.f};

    int base = 0;
    while (vdeg - base > 32) {                 // rare (P[deg>31] ~ 2e-4)
        chunk_full8<4>(t4, bk, base, sub, c4, a);
        base += 32;
    }
    {   // wave-uniform tail ladder: {32,24,16,8} slots
        const int rem = vdeg - base;
        if (rem > 24)      chunk_masked8<4>(t4, bk, base, sub, c4, deg, d, a);
        else if (rem > 16) chunk_masked8<3>(t4, bk, base, sub, c4, deg, d, a);
        else if (rem > 8)  chunk_masked8<2>(t4, bk, base, sub, c4, deg, d, a);
        else               chunk_masked8<1>(t4, bk, base, sub, c4, deg, d, a);
    }

    // reduce across the 8 edge slots (lane bits 3,4,5)
#pragma unroll
    for (int off = 8; off < 64; off <<= 1) {
#pragma unroll
        for (int j = 0; j < 4; j++) {
            a[j][0] += __shfl_xor(a[j][0], off);
            a[j][1] += __shfl_xor(a[j][1], off);
        }
    }

    if (sub == 0) {
        const float4* b4 = (const float4*)bias;
        float4 bb0 = b4[2 * c4], bb1 = b4[2 * c4 + 1];
        float4 r0, r1;
        r0.x = inorm * a[0][0] + bb0.x;
        r0.y = inorm * a[0][1] + bb0.y;
        r0.z = inorm * a[1][0] + bb0.z;
        r0.w = inorm * a[1][1] + bb0.w;
        r1.x = inorm * a[2][0] + bb1.x;
        r1.y = inorm * a[2][1] + bb1.y;
        r1.z = inorm * a[3][0] + bb1.z;
        r1.w = inorm * a[3][1] + bb1.w;
        st8(out, d, c4, r0, r1);
    }
}

// ---------------- fallback path (fp32, atomic CSR build) ----------------

__global__ void k_init_fb(int* __restrict__ a, int* __restrict__ b,
                          const int* __restrict__ ids, float* __restrict__ outid,
                          int n, int nid) {
    int i = blockIdx.x * blockDim.x + threadIdx.x;
    if (i < n) { a[i] = 0; b[i] = 0; }
    if (i < nid) outid[i] = (float)ids[i];
}

__global__ void k_histo(const int* __restrict__ src, const int* __restrict__ dst,
                        int* __restrict__ out_deg, int* __restrict__ in_deg, int n) {
    int i = blockIdx.x * blockDim.x + threadIdx.x;
    if (i < n) {
        atomicAdd(&out_deg[src[i]], 1);
        atomicAdd(&in_deg[dst[i]], 1);
    }
}

__global__ void k_scan_partial(const int* __restrict__ deg, int* __restrict__ block_sums, int n) {
    __shared__ int red[SCAN_BLOCK];
    const int t = threadIdx.x;
    const int base = blockIdx.x * SCAN_ELEMS + t * SCAN_ITEMS;
    int s = 0;
#pragma unroll
    for (int k = 0; k < SCAN_ITEMS; k++) {
        int i = base + k;
        if (i < n) s += deg[i];
    }
    red[t] = s;
    __syncthreads();
    for (int off = SCAN_BLOCK / 2; off > 0; off >>= 1) {
        if (t < off) red[t] += red[t + off];
        __syncthreads();
    }
    if (t == 0) block_sums[blockIdx.x] = red[0];
}

__global__ void k_scan_blocks(int* __restrict__ block_sums, int nb) {
    __shared__ int sh[SCAN_BLOCK];
    const int t = threadIdx.x;
    sh[t] = (t < nb) ? block_sums[t] : 0;
    __syncthreads();
    for (int off = 1; off < SCAN_BLOCK; off <<= 1) {
        int v = (t >= off) ? sh[t - off] : 0;
        __syncthreads();
        sh[t] += v;
        __syncthreads();
    }
    if (t < nb) block_sums[t] = (t == 0) ? 0 : sh[t - 1];
}

__global__ void k_scan_write(const int* __restrict__ deg, const int* __restrict__ block_off,
                             int* __restrict__ row_off, int* __restrict__ cursor, int n) {
    __shared__ int sh[SCAN_BLOCK];
    const int t = threadIdx.x;
    const int base = blockIdx.x * SCAN_ELEMS + t * SCAN_ITEMS;
    int v[SCAN_ITEMS];
    int s = 0;
#pragma unroll
    for (int k = 0; k < SCAN_ITEMS; k++) {
        int i = base + k;
        v[k] = (i < n) ? deg[i] : 0;
        s += v[k];
    }
    sh[t] = s;
    __syncthreads();
    for (int off = 1; off < SCAN_BLOCK; off <<= 1) {
        int x = (t >= off) ? sh[t - off] : 0;
        __syncthreads();
        sh[t] += x;
        __syncthreads();
    }
    int run = block_off[blockIdx.x] + ((t == 0) ? 0 : sh[t - 1]);
#pragma unroll
    for (int k = 0; k < SCAN_ITEMS; k++) {
        int i = base + k;
        if (i < n) { row_off[i] = run; cursor[i] = run; run += v[k]; }
    }
    if (blockIdx.x == gridDim.x - 1 && t == SCAN_BLOCK - 1) {
        row_off[n] = block_off[blockIdx.x] + sh[SCAN_BLOCK - 1];
    }
}

__global__ void k_scatter(const int* __restrict__ src, const int* __restrict__ dst,
                          int* __restrict__ cursor, int* __restrict__ csr_src, int n) {
    int i = blockIdx.x * blockDim.x + threadIdx.x;
    if (i < n) {
        int d = dst[i];
        int pos = atomicAdd(&cursor[d], 1);
        csr_src[pos] = src[i];
    }
}

template <int FIN>
__global__ void k_gemm_fb(const float* __restrict__ h, const int* __restrict__ out_deg,
                          const float* __restrict__ W, float* __restrict__ t) {
    __shared__ float sh[32 * FIN];
    __shared__ float sno[32];
    const int tid = threadIdx.x;
    const int block0 = blockIdx.x * 32;

    if (tid < 32) sno[tid] = rsqrtf((float)(out_deg[block0 + tid] + 1));
    __syncthreads();

    for (int idx = tid; idx < 32 * FIN; idx += 256) {
        int r = idx / FIN;
        int c = idx % FIN;
        sh[idx] = h[(size_t)(block0 + r) * FIN + c] * sno[r];
    }
    __syncthreads();

    const int j2 = tid & 31;
    const int rg = tid >> 5;
    const float2* W2 = (const float2*)W;
    float2 a0 = {0.f, 0.f}, a1 = {0.f, 0.f}, a2 = {0.f, 0.f}, a3 = {0.f, 0.f};
#pragma unroll 4
    for (int k = 0; k < FIN; k++) {
        float2 w = W2[k * 32 + j2];
        float s0 = sh[(rg + 0)  * FIN + k];
        float s1 = sh[(rg + 8)  * FIN + k];
        float s2 = sh[(rg + 16) * FIN + k];
        float s3 = sh[(rg + 24) * FIN + k];
        a0.x += s0 * w.x; a0.y += s0 * w.y;
        a1.x += s1 * w.x; a1.y += s1 * w.y;
        a2.x += s2 * w.x; a2.y += s2 * w.y;
        a3.x += s3 * w.x; a3.y += s3 * w.y;
    }
    float* tp = t + (size_t)block0 * FOUT;
    st2(tp, (rg + 0)  * 32 + j2, a0);
    st2(tp, (rg + 8)  * 32 + j2, a1);
    st2(tp, (rg + 16) * 32 + j2, a2);
    st2(tp, (rg + 24) * 32 + j2, a3);
}

__global__ void k_spmm_c(const float* __restrict__ t, const int* __restrict__ row_off,
                         const int* __restrict__ csr_src, const float* __restrict__ bias,
                         float* __restrict__ out) {
    const int wave = blockIdx.x * (blockDim.x >> 6) + (threadIdx.x >> 6);
    const int lane = threadIdx.x & 63;
    const int d = wave;
    const int e0 = row_off[d];
    const int e1 = row_off[d + 1];
    const float inorm = rsqrtf((float)(e1 - e0 + 1));

    float a0 = t[(size_t)d * FOUT + lane];
    float a1 = 0.f, a2 = 0.f, a3 = 0.f, a4 = 0.f, a5 = 0.f, a6 = 0.f, a7 = 0.f;
    int e = e0;
    for (; e + 8 <= e1; e += 8) {
        int s0 = csr_src[e + 0], s1 = csr_src[e + 1], s2 = csr_src[e + 2], s3 = csr_src[e + 3];
        int s4 = csr_src[e + 4], s5 = csr_src[e + 5], s6 = csr_src[e + 6], s7 = csr_src[e + 7];
        a0 += t[(size_t)s0 * FOUT + lane];
        a1 += t[(size_t)s1 * FOUT + lane];
        a2 += t[(size_t)s2 * FOUT + lane];
        a3 += t[(size_t)s3 * FOUT + lane];
        a4 += t[(size_t)s4 * FOUT + lane];
        a5 += t[(size_t)s5 * FOUT + lane];
        a6 += t[(size_t)s6 * FOUT + lane];
        a7 += t[(size_t)s7 * FOUT + lane];
    }
    for (; e + 4 <= e1; e += 4) {
        int s0 = csr_src[e + 0], s1 = csr_src[e + 1], s2 = csr_src[e + 2], s3 = csr_src[e + 3];
        a0 += t[(size_t)s0 * FOUT + lane];
        a1 += t[(size_t)s1 * FOUT + lane];
        a2 += t[(size_t)s2 * FOUT + lane];
        a3 += t[(size_t)s3 * FOUT + lane];
    }
    for (; e < e1; e++) a0 += t[(size_t)csr_src[e] * FOUT + lane];

    float acc = ((a0 + a1) + (a2 + a3)) + ((a4 + a5) + (a6 + a7));
    out[(size_t)d * FOUT + lane] = inorm * acc + bias[lane];
}

// ---------------- launch ----------------

extern "C" void kernel_launch(void* const* d_in, const int* in_sizes, int n_in,
                              void* d_out, int out_size, void* d_ws, size_t ws_size,
                              hipStream_t stream) {
    const float* h   = (const float*)d_in[0];
    const int*   src = (const int*)d_in[1];
    const int*   dst = (const int*)d_in[2];
    const int*   ids = (const int*)d_in[3];
    const float* W0  = (const float*)d_in[4];
    const float* b0  = (const float*)d_in[5];
    const float* W1  = (const float*)d_in[6];
    const float* b1  = (const float*)d_in[7];
    const float* W2  = (const float*)d_in[8];
    const float* b2  = (const float*)d_in[9];
    const int N = N_NODES;
    const int E = in_sizes[1];

    size_t o = 0;
    auto alloc = [&](size_t nbytes) -> void* {
        void* p = (char*)d_ws + o;
        o += (nbytes + 255) & ~(size_t)255;
        return p;
    };

    float* outp = (float*)d_out;
    const int B = 256;
    const int spmmGrid = N / 4;            // 25000 blocks x 4 waves
    const int gemmGrid = (N / 16 + 3) / 4; // 6250 wave-tiles, 4 waves/block -> 1563

    // fixed partition capacity: mean + huge slack, rounded to 256
    const int capP = (((E / NPART) * 9) / 8 + 512 + 255) & ~255;
    const size_t streamEnt = (size_t)NPART * capP;

    const size_t needNew =
        ((streamEnt * 4 + 255) & ~(size_t)255) +           // dstStream
        ((streamEnt * 2 + 255) & ~(size_t)255) +           // srcStream
        ((streamEnt * 4 + 255) & ~(size_t)255) +           // csr_src
        (((size_t)N * 8 + 255) & ~(size_t)255) +           // rowdeg
        (((size_t)N * 4 + 255) & ~(size_t)255) +           // out_deg
        2 * 1024 +                                          // cursors
        2 * (((size_t)(N + 1) * FOUT * 2 + 255) & ~(size_t)255) +  // t, hbuf
        64 * 1024 + 4096;

    if (ws_size >= needNew) {
        // ---------- single-pass partitioned build + register-W gemm + 16B-gather spmm ----------
        unsigned int*   dstStream = (unsigned int*)alloc(streamEnt * 4);
        unsigned short* srcStream = (unsigned short*)alloc(streamEnt * 2);
        int*            csr_src   = (int*)alloc(streamEnt * 4);
        int2*           rowdeg    = (int2*)alloc((size_t)N * 8);
        int*            out_deg   = (int*)alloc((size_t)N * 4);
        int*            dstCur    = (int*)alloc(1024);
        int*            srcCur    = (int*)alloc(1024);
        unsigned short* t         = (unsigned short*)alloc((size_t)(N + 1) * FOUT * 2);  // +1 zero row
        unsigned short* hbuf      = (unsigned short*)alloc((size_t)N * FOUT * 2);
        unsigned short* Wt0       = (unsigned short*)alloc(128 * 64 * 2);
        unsigned short* Wt1       = (unsigned short*)alloc(64 * 64 * 2);
        unsigned short* Wt2       = (unsigned short*)alloc(64 * 64 * 2);

        const int nTiles = (E + TILE - 1) / TILE;   // 196

        k_setup<<<32, B, 0, stream>>>(W0, W1, W2, Wt0, Wt1, Wt2,
                                      (unsigned int*)(t + (size_t)N * FOUT),
                                      dstCur, srcCur, capP,
                                      ids, outp + (size_t)N * FOUT, 1024);
        k_binscatter<<<nTiles, 1024, 0, stream>>>(src, dst, dstCur, srcCur, dstStream, srcStream, E);
        k_csr_odeg<<<2 * NPART, 512, 0, stream>>>(dstStream, srcStream, dstCur, srcCur, capP,
                                                  rowdeg, csr_src, out_deg);

        // layer 0: 128 -> 64 (fp32 in, bf16 out)
        k_gemm_reg<128, float, unsigned short><<<gemmGrid, B, 0, stream>>>(h, out_deg, Wt0, t);
        k_spmm_b<unsigned short><<<spmmGrid, B, 0, stream>>>((const uint4*)t, rowdeg, csr_src, b0, hbuf);
        // layer 1
        k_gemm_reg<64, unsigned short, unsigned short><<<gemmGrid, B, 0, stream>>>(hbuf, out_deg, Wt1, t);
        k_spmm_b<unsigned short><<<spmmGrid, B, 0, stream>>>((const uint4*)t, rowdeg, csr_src, b1, hbuf);
        // layer 2 (fp32 final out)
        k_gemm_reg<64, unsigned short, unsigned short><<<gemmGrid, B, 0, stream>>>(hbuf, out_deg, Wt2, t);
        k_spmm_b<float><<<spmmGrid, B, 0, stream>>>((const uint4*)t, rowdeg, csr_src, b2, outp);
    } else {
        // ---------- CSR fallback (fp32, atomic build) ----------
        int*   in_deg  = (int*)alloc((size_t)N * 4);
        int*   out_deg = (int*)alloc((size_t)N * 4);
        int*   row_off = (int*)alloc((size_t)(N + 1) * 4);
        int*   cursor  = (int*)alloc((size_t)N * 4);
        int*   csr_src = (int*)alloc((size_t)E * 4);
        float* t       = (float*)alloc((size_t)N * FOUT * 4);
        float* hbuf    = (float*)alloc((size_t)N * FOUT * 4);
        int*   bsums   = (int*)alloc((size_t)SCAN_BLOCK * 4);

        const int gN = (N + B - 1) / B;
        const int gE = (E + B - 1) / B;
        const int nScanBlocks = (N + SCAN_ELEMS - 1) / SCAN_ELEMS;

        k_init_fb<<<gN, B, 0, stream>>>(in_deg, out_deg, ids, outp + (size_t)N * FOUT, N, 1024);
        k_histo<<<gE, B, 0, stream>>>(src, dst, out_deg, in_deg, E);
        k_scan_partial<<<nScanBlocks, SCAN_BLOCK, 0, stream>>>(in_deg, bsums, N);
        k_scan_blocks<<<1, SCAN_BLOCK, 0, stream>>>(bsums, nScanBlocks);
        k_scan_write<<<nScanBlocks, SCAN_BLOCK, 0, stream>>>(in_deg, bsums, row_off, cursor, N);
        k_scatter<<<gE, B, 0, stream>>>(src, dst, cursor, csr_src, E);

        k_gemm_fb<128><<<N / 32, 256, 0, stream>>>(h, out_deg, W0, t);
        k_spmm_c<<<spmmGrid, 256, 0, stream>>>(t, row_off, csr_src, b0, hbuf);
        k_gemm_fb<64><<<N / 32, 256, 0, stream>>>(hbuf, out_deg, W1, t);
        k_spmm_c<<<spmmGrid, 256, 0, stream>>>(t, row_off, csr_src, b1, hbuf);
        k_gemm_fb<64><<<N / 32, 256, 0, stream>>>(hbuf, out_deg, W2, t);
        k_spmm_c<<<spmmGrid, 256, 0, stream>>>(t, row_off, csr_src, b2, outp);
    }
}

// Round 8
// 295.157 us; speedup vs baseline: 1.2273x; 1.0220x over previous
//
#include <hip/hip_runtime.h>

#define N_NODES 100000
#define FOUT 64

// partitioned-build constants
#define PSHIFT 9
#define PSIZE  512
#define NPART  ((N_NODES + PSIZE - 1) / PSIZE)   // 196
#define TILE   8192
#define SRCBITS 17
#define SRCMASK 0x1FFFF

#define SCAN_BLOCK 256
#define SCAN_ITEMS 8
#define SCAN_ELEMS (SCAN_BLOCK * SCAN_ITEMS)

typedef __attribute__((ext_vector_type(8))) short bf16x8;
typedef __attribute__((ext_vector_type(4))) float f32x4;
typedef __attribute__((ext_vector_type(2))) float f32x2;

// ---------------- bf16 helpers (manual, RNE) ----------------

static __device__ __forceinline__ float bf2f(unsigned short u) {
    union { unsigned int i; float f; } v;
    v.i = (unsigned int)u << 16;
    return v.f;
}
static __device__ __forceinline__ unsigned short f2bf(float f) {
    union { float f; unsigned int i; } v;
    v.f = f;
    unsigned int r = (v.i + 0x7fffu + ((v.i >> 16) & 1u)) >> 16;
    return (unsigned short)r;
}
static __device__ __forceinline__ unsigned int pk2(float x, float y) {
    return (unsigned int)f2bf(x) | ((unsigned int)f2bf(y) << 16);
}
// unpack one uint (2 bf16) -> f32x2 {low, high}
static __device__ __forceinline__ f32x2 up2v(unsigned int u) {
    union { unsigned int i; float f; } lo, hi;
    lo.i = u << 16;
    hi.i = u & 0xffff0000u;
    f32x2 r; r[0] = lo.f; r[1] = hi.f;
    return r;
}

template <typename T> static __device__ __forceinline__ void stf(T* p, float v);
template <> __device__ __forceinline__ void stf<float>(float* p, float v) { *p = v; }
template <> __device__ __forceinline__ void stf<unsigned short>(unsigned short* p, float v) { *p = f2bf(v); }

static __device__ __forceinline__ void st2(float* base, int idx, float2 v) {
    ((float2*)base)[idx] = v;
}
static __device__ __forceinline__ void st2(unsigned short* base, int idx, float2 v) {
    ((unsigned int*)base)[idx] = pk2(v.x, v.y);
}

// 8-col row store (fp32 or packed bf16) at row d, uint4-slot c4
static __device__ __forceinline__ void st8(float* base, int d, int c4,
                                           const float4& r0, const float4& r1) {
    ((float4*)base)[(size_t)d * 16 + 2 * c4]     = r0;
    ((float4*)base)[(size_t)d * 16 + 2 * c4 + 1] = r1;
}
static __device__ __forceinline__ void st8(unsigned short* base, int d, int c4,
                                           const float4& r0, const float4& r1) {
    uint4 u;
    u.x = pk2(r0.x, r0.y); u.y = pk2(r0.z, r0.w);
    u.z = pk2(r1.x, r1.y); u.w = pk2(r1.z, r1.w);
    ((uint4*)base)[(size_t)d * 8 + c4] = u;
}

// A-fragment load: 8 contiguous elems of one h row -> bf16x8
template <typename TIN> static __device__ __forceinline__ bf16x8 ldA(const TIN* p);
template <> __device__ __forceinline__ bf16x8 ldA<unsigned short>(const unsigned short* p) {
    return *(const bf16x8*)p;
}
template <> __device__ __forceinline__ bf16x8 ldA<float>(const float* p) {
    const f32x4* q = (const f32x4*)p;
    f32x4 lo = q[0], hi = q[1];
    bf16x8 a;
    a[0] = (short)f2bf(lo[0]); a[1] = (short)f2bf(lo[1]);
    a[2] = (short)f2bf(lo[2]); a[3] = (short)f2bf(lo[3]);
    a[4] = (short)f2bf(hi[0]); a[5] = (short)f2bf(hi[1]);
    a[6] = (short)f2bf(hi[2]); a[7] = (short)f2bf(hi[3]);
    return a;
}

// wave-level inclusive scan (64 lanes) via shfl_up
static __device__ __forceinline__ int wave_iscan(int x, int lane) {
#pragma unroll
    for (int off = 1; off < 64; off <<= 1) {
        int y = __shfl_up(x, off);
        if (lane >= off) x += y;
    }
    return x;
}

// ---------------- setup: W->bf16 transposed, sentinel row, cursors, ids ----------------

__global__ void k_setup(const float* __restrict__ W0, const float* __restrict__ W1,
                        const float* __restrict__ W2,
                        unsigned short* __restrict__ Wt0, unsigned short* __restrict__ Wt1,
                        unsigned short* __restrict__ Wt2, unsigned int* __restrict__ tzero,
                        int* __restrict__ dstCur, int* __restrict__ srcCur, int capP,
                        const int* __restrict__ ids, float* __restrict__ outid, int nid) {
    int i = blockIdx.x * blockDim.x + threadIdx.x;
    if (i < 128 * 64) {
        int k = i >> 6, n = i & 63;
        Wt0[n * 128 + k] = f2bf(W0[i]);
    }
    if (i < 64 * 64) {
        int k = i >> 6, n = i & 63;
        Wt1[n * 64 + k] = f2bf(W1[i]);
        Wt2[n * 64 + k] = f2bf(W2[i]);
    }
    if (i < 32) tzero[i] = 0u;   // 128 B zero row at t[N_NODES]
    if (i < NPART) { dstCur[i] = i * capP; srcCur[i] = i * capP; }
    if (i < nid) outid[i] = (float)ids[i];
}

// ---------------- partitioned build (single pass, fixed-capacity partitions) ----------------

// per-tile LDS scatter into bin-contiguous staging; wave-per-bin coalesced flush.
// Scans are wave-shuffle based: 2 block barriers instead of ~32.
__global__ void __launch_bounds__(1024) k_binscatter(
        const int* __restrict__ src, const int* __restrict__ dst,
        int* __restrict__ dstCur, int* __restrict__ srcCur,
        unsigned int* __restrict__ dstStream,
        unsigned short* __restrict__ srcStream, int E) {
    __shared__ unsigned int   stageD[TILE];    // 32 KB
    __shared__ unsigned short stageS[TILE];    // 16 KB
    __shared__ int dh[NPART], sh2[NPART];
    __shared__ int dLoc[NPART], sLoc[NPART];
    __shared__ int dBase[NPART], sBase[NPART];
    __shared__ int dcur[NPART], scur[NPART];
    __shared__ int sbufD[4], sbufS[4];

    const int tid = threadIdx.x;
    const int lane = tid & 63;
    const int w = tid >> 6;
    const int base = blockIdx.x * TILE;
    const int end = min(base + TILE, E);

    if (tid < NPART) { dh[tid] = 0; sh2[tid] = 0; }
    __syncthreads();

    for (int j = base + tid; j < end; j += 1024) {
        atomicAdd(&dh[dst[j] >> PSHIFT], 1);
        atomicAdd(&sh2[src[j] >> PSHIFT], 1);
    }
    __syncthreads();

    // dual shuffle scans (dst + src partition counts), one LDS cross-wave fix
    {
        int vD = 0, vS = 0;
        if (tid < NPART) { vD = dh[tid]; vS = sh2[tid]; }
        int xD = wave_iscan(vD, lane);
        int xS = wave_iscan(vS, lane);
        if (tid < 256 && lane == 63) { sbufD[w] = xD; sbufS[w] = xS; }
        __syncthreads();
        if (tid < NPART) {
            int addD = 0, addS = 0;
            for (int j = 0; j < w; j++) { addD += sbufD[j]; addS += sbufS[j]; }
            int incD = xD + addD;
            int incS = xS + addS;
            dLoc[tid] = incD - vD;
            dcur[tid] = incD - vD;
            dBase[tid] = vD ? atomicAdd(&dstCur[tid], vD) : 0;
            sLoc[tid] = incS - vS;
            scur[tid] = incS - vS;
            sBase[tid] = vS ? atomicAdd(&srcCur[tid], vS) : 0;
        }
        __syncthreads();
    }

    for (int j = base + tid; j < end; j += 1024) {
        int s = src[j], d = dst[j];
        int pd = atomicAdd(&dcur[d >> PSHIFT], 1);
        stageD[pd] = ((unsigned int)(d & (PSIZE - 1)) << SRCBITS) | (unsigned int)s;
        int ps = atomicAdd(&scur[s >> PSHIFT], 1);
        stageS[ps] = (unsigned short)(s & (PSIZE - 1));
    }
    __syncthreads();

    for (int b = w; b < NPART; b += 16) {
        const int cnt  = dh[b];
        const int loc  = dLoc[b];
        unsigned int* gd = dstStream + dBase[b];
        for (int i = lane; i < cnt; i += 64) gd[i] = stageD[loc + i];
        const int cnt2 = sh2[b];
        const int loc2 = sLoc[b];
        unsigned short* gs = srcStream + sBase[b];
        for (int i = lane; i < cnt2; i += 64) gs[i] = stageS[loc2 + i];
    }
}

// fused: blocks [0,NPART) counting-sort dst partitions -> rowdeg{off,vdeg} + csr_src
//        (self-loop materialized at row start; row has deg+1 entries);
//        blocks [NPART,2*NPART) histogram src partitions -> out_deg.
__global__ void k_csr_odeg(const unsigned int* __restrict__ dstStream,
                           const unsigned short* __restrict__ srcStream,
                           const int* __restrict__ dstCur, const int* __restrict__ srcCur,
                           int capP,
                           int2* __restrict__ rowdeg, int* __restrict__ csr_src,
                           int* __restrict__ out_deg) {
    __shared__ int hist[PSIZE];
    __shared__ int sbuf8[8];
    const int tid = threadIdx.x;

    if (blockIdx.x < NPART) {
        const int p = blockIdx.x;
        const int nodeBase = p << PSHIFT;
        const int nN = min(PSIZE, N_NODES - nodeBase);
        const int e0 = p * capP;
        const int e1 = dstCur[p];

        for (int i = tid; i < PSIZE; i += 512) hist[i] = 0;
        __syncthreads();
        for (int e = e0 + tid; e < e1; e += 512)
            atomicAdd(&hist[dstStream[e] >> SRCBITS], 1);
        __syncthreads();

        // scan over (deg+1) per node: reserves a self-loop slot at each row start
        const int lane = tid & 63;
        const int w = tid >> 6;
        int c = hist[tid];
        int v = c + 1;
        int x = wave_iscan(v, lane);
        if (lane == 63) sbuf8[w] = x;
        __syncthreads();
        int add = 0;
        for (int j = 0; j < w; j++) add += sbuf8[j];
        int run = x + add - v;              // exclusive start within partition
        hist[tid] = run + 1;                // scatter cursor (after self edge)
        if (tid < nN) {
            rowdeg[nodeBase + tid] = make_int2(e0 + run, v);     // {off, vdeg}
            csr_src[e0 + run] = nodeBase + tid;                  // self edge
        }
        __syncthreads();

        for (int e = e0 + tid; e < e1; e += 512) {
            unsigned int rec = dstStream[e];
            int d = rec >> SRCBITS;
            int sv = rec & SRCMASK;
            int pos = atomicAdd(&hist[d], 1);
            csr_src[e0 + pos] = sv;
        }
    } else {
        const int p = blockIdx.x - NPART;
        const int nodeBase = p << PSHIFT;
        const int nN = min(PSIZE, N_NODES - nodeBase);
        const int e0 = p * capP;
        const int e1 = srcCur[p];

        for (int i = tid; i < PSIZE; i += 512) hist[i] = 0;
        __syncthreads();
        for (int e = e0 + tid; e < e1; e += 512)
            atomicAdd(&hist[srcStream[e]], 1);
        __syncthreads();
        if (tid < nN) out_deg[nodeBase + tid] = hist[tid];
    }
}

// ---------------- register-W MFMA gemm (no LDS, no barriers) ----------------
// t[r][:] = rsqrt(out_deg[r]+1) * (h[r][:] @ W)   -- out-norm commuted to output rows.
template <int FIN, typename TIN, typename TOUT>
__global__ void k_gemm_reg(const TIN* __restrict__ h, const int* __restrict__ out_deg,
                           const unsigned short* __restrict__ Wt, TOUT* __restrict__ t) {
    constexpr int NKC = FIN / 32;
    const int lane = threadIdx.x & 63;
    const int m = lane & 15;
    const int q = lane >> 4;
    const int wid = blockIdx.x * (blockDim.x >> 6) + (threadIdx.x >> 6);
    const int nw = (gridDim.x * blockDim.x) >> 6;
    const int nTiles = N_NODES / 16;    // 6250 exact

    bf16x8 bfrag[NKC][4];
#pragma unroll
    for (int kc = 0; kc < NKC; kc++)
#pragma unroll
        for (int nt = 0; nt < 4; nt++)
            bfrag[kc][nt] = *(const bf16x8*)&Wt[(nt * 16 + m) * FIN + kc * 32 + q * 8];

    for (int tile = wid; tile < nTiles; tile += nw) {
        const TIN* hrow = h + (size_t)(tile * 16 + m) * FIN + q * 8;
        f32x4 acc[4];
#pragma unroll
        for (int nt = 0; nt < 4; nt++) acc[nt] = (f32x4){0.f, 0.f, 0.f, 0.f};
#pragma unroll
        for (int kc = 0; kc < NKC; kc++) {
            bf16x8 a = ldA(hrow + kc * 32);
#pragma unroll
            for (int nt = 0; nt < 4; nt++)
                acc[nt] = __builtin_amdgcn_mfma_f32_16x16x32_bf16(a, bfrag[kc][nt], acc[nt], 0, 0, 0);
        }
        const int r0 = tile * 16 + q * 4;
        int4 dg = *(const int4*)&out_deg[r0];
        float s0 = rsqrtf((float)(dg.x + 1));
        float s1 = rsqrtf((float)(dg.y + 1));
        float s2 = rsqrtf((float)(dg.z + 1));
        float s3 = rsqrtf((float)(dg.w + 1));
#pragma unroll
        for (int nt = 0; nt < 4; nt++) {
            TOUT* tp = t + (size_t)r0 * FOUT + nt * 16 + m;
            stf(tp + 0 * FOUT, acc[nt][0] * s0);
            stf(tp + 1 * FOUT, acc[nt][1] * s1);
            stf(tp + 2 * FOUT, acc[nt][2] * s2);
            stf(tp + 3 * FOUT, acc[nt][3] * s3);
        }
    }
}

// ---------------- CSR SpMM: 8 slots x dwordx4, self-loop in CSR, sentinel masking ----------------
// 8 lanes x uint4 = one 128B bf16 row per edge slot; 8 slots/wave.
// Row has vdeg = deg+1 entries (self edge materialized); i>=vdeg gathers zero row t[N].

static __device__ __forceinline__ void accum8(f32x2* a, uint4 v) {
    a[0] += up2v(v.x);
    a[1] += up2v(v.y);
    a[2] += up2v(v.z);
    a[3] += up2v(v.w);
}

template <int G>   // G groups of 8 edges, unmasked
static __device__ __forceinline__ void chunk_full8(
        const uint4* __restrict__ t4, const int* __restrict__ bk,
        int base, int sub, int c4, f32x2* acc) {
    int s[G];
#pragma unroll
    for (int u = 0; u < G; u++) s[u] = bk[base + sub + 8 * u];
    uint4 v[G];
#pragma unroll
    for (int u = 0; u < G; u++) v[u] = t4[(size_t)s[u] * 8 + c4];
#pragma unroll
    for (int u = 0; u < G; u++) accum8(acc, v[u]);
}

template <int G>   // G groups of 8 edges, masked via sentinel row
static __device__ __forceinline__ void chunk_masked8(
        const uint4* __restrict__ t4, const int* __restrict__ bk,
        int base, int sub, int c4, int vdeg, f32x2* acc) {
    int s[G];
#pragma unroll
    for (int u = 0; u < G; u++) {
        int i = base + sub + 8 * u;
        int sv = bk[i];                       // may read pad: value discarded below
        s[u] = (i < vdeg) ? sv : N_NODES;
    }
    uint4 v[G];
#pragma unroll
    for (int u = 0; u < G; u++) v[u] = t4[(size_t)s[u] * 8 + c4];
#pragma unroll
    for (int u = 0; u < G; u++) accum8(acc, v[u]);
}

template <typename TOUT>
__global__ void k_spmm_b(const uint4* __restrict__ t4,   // bf16 rows, N+1 rows (row N = 0)
                         const int2* __restrict__ rowdeg, const int* __restrict__ csr_src,
                         const float* __restrict__ bias, TOUT* __restrict__ out) {
    const int wave = blockIdx.x * (blockDim.x >> 6) + (threadIdx.x >> 6);
    const int lane = threadIdx.x & 63;
    const int sub = lane >> 3;      // edge slot 0..7
    const int c4 = lane & 7;        // uint4 index within row (cols 8*c4 .. 8*c4+7)
    const int d = wave;
    const int2 rd = rowdeg[d];
    const int e0 = rd.x;
    const int vdeg = rd.y;          // deg+1 (self included)
    const float inorm = rsqrtf((float)vdeg);
    const int* bk = csr_src + e0;

    f32x2 a[4];
#pragma unroll
    for (int j = 0; j < 4; j++) a[j] = (f32x2){0.f, 0.f};

    int base = 0;
    while (vdeg - base > 32) {                 // rare (P[deg>31] ~ 2e-4)
        chunk_full8<4>(t4, bk, base, sub, c4, a);
        base += 32;
    }
    {   // wave-uniform tail ladder: {32,24,16,8} slots
        const int rem = vdeg - base;
        if (rem > 24)      chunk_masked8<4>(t4, bk, base, sub, c4, vdeg, a);
        else if (rem > 16) chunk_masked8<3>(t4, bk, base, sub, c4, vdeg, a);
        else if (rem > 8)  chunk_masked8<2>(t4, bk, base, sub, c4, vdeg, a);
        else               chunk_masked8<1>(t4, bk, base, sub, c4, vdeg, a);
    }

    // reduce across the 8 edge slots (lane bits 3,4,5)
#pragma unroll
    for (int off = 8; off < 64; off <<= 1) {
#pragma unroll
        for (int j = 0; j < 4; j++) {
            a[j][0] += __shfl_xor(a[j][0], off);
            a[j][1] += __shfl_xor(a[j][1], off);
        }
    }

    if (sub == 0) {
        const float4* b4 = (const float4*)bias;
        float4 bb0 = b4[2 * c4], bb1 = b4[2 * c4 + 1];
        float4 r0, r1;
        r0.x = inorm * a[0][0] + bb0.x;
        r0.y = inorm * a[0][1] + bb0.y;
        r0.z = inorm * a[1][0] + bb0.z;
        r0.w = inorm * a[1][1] + bb0.w;
        r1.x = inorm * a[2][0] + bb1.x;
        r1.y = inorm * a[2][1] + bb1.y;
        r1.z = inorm * a[3][0] + bb1.z;
        r1.w = inorm * a[3][1] + bb1.w;
        st8(out, d, c4, r0, r1);
    }
}

// ---------------- fallback path (fp32, atomic CSR build) ----------------

__global__ void k_init_fb(int* __restrict__ a, int* __restrict__ b,
                          const int* __restrict__ ids, float* __restrict__ outid,
                          int n, int nid) {
    int i = blockIdx.x * blockDim.x + threadIdx.x;
    if (i < n) { a[i] = 0; b[i] = 0; }
    if (i < nid) outid[i] = (float)ids[i];
}

__global__ void k_histo(const int* __restrict__ src, const int* __restrict__ dst,
                        int* __restrict__ out_deg, int* __restrict__ in_deg, int n) {
    int i = blockIdx.x * blockDim.x + threadIdx.x;
    if (i < n) {
        atomicAdd(&out_deg[src[i]], 1);
        atomicAdd(&in_deg[dst[i]], 1);
    }
}

__global__ void k_scan_partial(const int* __restrict__ deg, int* __restrict__ block_sums, int n) {
    __shared__ int red[SCAN_BLOCK];
    const int t = threadIdx.x;
    const int base = blockIdx.x * SCAN_ELEMS + t * SCAN_ITEMS;
    int s = 0;
#pragma unroll
    for (int k = 0; k < SCAN_ITEMS; k++) {
        int i = base + k;
        if (i < n) s += deg[i];
    }
    red[t] = s;
    __syncthreads();
    for (int off = SCAN_BLOCK / 2; off > 0; off >>= 1) {
        if (t < off) red[t] += red[t + off];
        __syncthreads();
    }
    if (t == 0) block_sums[blockIdx.x] = red[0];
}

__global__ void k_scan_blocks(int* __restrict__ block_sums, int nb) {
    __shared__ int sh[SCAN_BLOCK];
    const int t = threadIdx.x;
    sh[t] = (t < nb) ? block_sums[t] : 0;
    __syncthreads();
    for (int off = 1; off < SCAN_BLOCK; off <<= 1) {
        int v = (t >= off) ? sh[t - off] : 0;
        __syncthreads();
        sh[t] += v;
        __syncthreads();
    }
    if (t < nb) block_sums[t] = (t == 0) ? 0 : sh[t - 1];
}

__global__ void k_scan_write(const int* __restrict__ deg, const int* __restrict__ block_off,
                             int* __restrict__ row_off, int* __restrict__ cursor, int n) {
    __shared__ int sh[SCAN_BLOCK];
    const int t = threadIdx.x;
    const int base = blockIdx.x * SCAN_ELEMS + t * SCAN_ITEMS;
    int v[SCAN_ITEMS];
    int s = 0;
#pragma unroll
    for (int k = 0; k < SCAN_ITEMS; k++) {
        int i = base + k;
        v[k] = (i < n) ? deg[i] : 0;
        s += v[k];
    }
    sh[t] = s;
    __syncthreads();
    for (int off = 1; off < SCAN_BLOCK; off <<= 1) {
        int x = (t >= off) ? sh[t - off] : 0;
        __syncthreads();
        sh[t] += x;
        __syncthreads();
    }
    int run = block_off[blockIdx.x] + ((t == 0) ? 0 : sh[t - 1]);
#pragma unroll
    for (int k = 0; k < SCAN_ITEMS; k++) {
        int i = base + k;
        if (i < n) { row_off[i] = run; cursor[i] = run; run += v[k]; }
    }
    if (blockIdx.x == gridDim.x - 1 && t == SCAN_BLOCK - 1) {
        row_off[n] = block_off[blockIdx.x] + sh[SCAN_BLOCK - 1];
    }
}

__global__ void k_scatter(const int* __restrict__ src, const int* __restrict__ dst,
                          int* __restrict__ cursor, int* __restrict__ csr_src, int n) {
    int i = blockIdx.x * blockDim.x + threadIdx.x;
    if (i < n) {
        int d = dst[i];
        int pos = atomicAdd(&cursor[d], 1);
        csr_src[pos] = src[i];
    }
}

template <int FIN>
__global__ void k_gemm_fb(const float* __restrict__ h, const int* __restrict__ out_deg,
                          const float* __restrict__ W, float* __restrict__ t) {
    __shared__ float sh[32 * FIN];
    __shared__ float sno[32];
    const int tid = threadIdx.x;
    const int block0 = blockIdx.x * 32;

    if (tid < 32) sno[tid] = rsqrtf((float)(out_deg[block0 + tid] + 1));
    __syncthreads();

    for (int idx = tid; idx < 32 * FIN; idx += 256) {
        int r = idx / FIN;
        int c = idx % FIN;
        sh[idx] = h[(size_t)(block0 + r) * FIN + c] * sno[r];
    }
    __syncthreads();

    const int j2 = tid & 31;
    const int rg = tid >> 5;
    const float2* W2 = (const float2*)W;
    float2 a0 = {0.f, 0.f}, a1 = {0.f, 0.f}, a2 = {0.f, 0.f}, a3 = {0.f, 0.f};
#pragma unroll 4
    for (int k = 0; k < FIN; k++) {
        float2 w = W2[k * 32 + j2];
        float s0 = sh[(rg + 0)  * FIN + k];
        float s1 = sh[(rg + 8)  * FIN + k];
        float s2 = sh[(rg + 16) * FIN + k];
        float s3 = sh[(rg + 24) * FIN + k];
        a0.x += s0 * w.x; a0.y += s0 * w.y;
        a1.x += s1 * w.x; a1.y += s1 * w.y;
        a2.x += s2 * w.x; a2.y += s2 * w.y;
        a3.x += s3 * w.x; a3.y += s3 * w.y;
    }
    float* tp = t + (size_t)block0 * FOUT;
    st2(tp, (rg + 0)  * 32 + j2, a0);
    st2(tp, (rg + 8)  * 32 + j2, a1);
    st2(tp, (rg + 16) * 32 + j2, a2);
    st2(tp, (rg + 24) * 32 + j2, a3);
}

__global__ void k_spmm_c(const float* __restrict__ t, const int* __restrict__ row_off,
                         const int* __restrict__ csr_src, const float* __restrict__ bias,
                         float* __restrict__ out) {
    const int wave = blockIdx.x * (blockDim.x >> 6) + (threadIdx.x >> 6);
    const int lane = threadIdx.x & 63;
    const int d = wave;
    const int e0 = row_off[d];
    const int e1 = row_off[d + 1];
    const float inorm = rsqrtf((float)(e1 - e0 + 1));

    float a0 = t[(size_t)d * FOUT + lane];
    float a1 = 0.f, a2 = 0.f, a3 = 0.f, a4 = 0.f, a5 = 0.f, a6 = 0.f, a7 = 0.f;
    int e = e0;
    for (; e + 8 <= e1; e += 8) {
        int s0 = csr_src[e + 0], s1 = csr_src[e + 1], s2 = csr_src[e + 2], s3 = csr_src[e + 3];
        int s4 = csr_src[e + 4], s5 = csr_src[e + 5], s6 = csr_src[e + 6], s7 = csr_src[e + 7];
        a0 += t[(size_t)s0 * FOUT + lane];
        a1 += t[(size_t)s1 * FOUT + lane];
        a2 += t[(size_t)s2 * FOUT + lane];
        a3 += t[(size_t)s3 * FOUT + lane];
        a4 += t[(size_t)s4 * FOUT + lane];
        a5 += t[(size_t)s5 * FOUT + lane];
        a6 += t[(size_t)s6 * FOUT + lane];
        a7 += t[(size_t)s7 * FOUT + lane];
    }
    for (; e + 4 <= e1; e += 4) {
        int s0 = csr_src[e + 0], s1 = csr_src[e + 1], s2 = csr_src[e + 2], s3 = csr_src[e + 3];
        a0 += t[(size_t)s0 * FOUT + lane];
        a1 += t[(size_t)s1 * FOUT + lane];
        a2 += t[(size_t)s2 * FOUT + lane];
        a3 += t[(size_t)s3 * FOUT + lane];
    }
    for (; e < e1; e++) a0 += t[(size_t)csr_src[e] * FOUT + lane];

    float acc = ((a0 + a1) + (a2 + a3)) + ((a4 + a5) + (a6 + a7));
    out[(size_t)d * FOUT + lane] = inorm * acc + bias[lane];
}

// ---------------- launch ----------------

extern "C" void kernel_launch(void* const* d_in, const int* in_sizes, int n_in,
                              void* d_out, int out_size, void* d_ws, size_t ws_size,
                              hipStream_t stream) {
    const float* h   = (const float*)d_in[0];
    const int*   src = (const int*)d_in[1];
    const int*   dst = (const int*)d_in[2];
    const int*   ids = (const int*)d_in[3];
    const float* W0  = (const float*)d_in[4];
    const float* b0  = (const float*)d_in[5];
    const float* W1  = (const float*)d_in[6];
    const float* b1  = (const float*)d_in[7];
    const float* W2  = (const float*)d_in[8];
    const float* b2  = (const float*)d_in[9];
    const int N = N_NODES;
    const int E = in_sizes[1];

    size_t o = 0;
    auto alloc = [&](size_t nbytes) -> void* {
        void* p = (char*)d_ws + o;
        o += (nbytes + 255) & ~(size_t)255;
        return p;
    };

    float* outp = (float*)d_out;
    const int B = 256;
    const int spmmGrid = N / 4;            // 25000 blocks x 4 waves
    const int gemmGrid = (N / 16 + 3) / 4; // 6250 wave-tiles, 4 waves/block -> 1563

    // fixed partition capacity: max edges/partition + PSIZE self slots + slack
    const int capP = (((E / NPART) * 9) / 8 + 1024 + 255) & ~255;
    const size_t streamEnt = (size_t)NPART * capP;

    const size_t needNew =
        ((streamEnt * 4 + 255) & ~(size_t)255) +           // dstStream
        ((streamEnt * 2 + 255) & ~(size_t)255) +           // srcStream
        ((streamEnt * 4 + 255) & ~(size_t)255) +           // csr_src
        (((size_t)N * 8 + 255) & ~(size_t)255) +           // rowdeg
        (((size_t)N * 4 + 255) & ~(size_t)255) +           // out_deg
        2 * 1024 +                                          // cursors
        2 * (((size_t)(N + 1) * FOUT * 2 + 255) & ~(size_t)255) +  // t, hbuf
        64 * 1024 + 4096;

    if (ws_size >= needNew) {
        // ---------- single-pass partitioned build + register-W gemm + 16B-gather spmm ----------
        unsigned int*   dstStream = (unsigned int*)alloc(streamEnt * 4);
        unsigned short* srcStream = (unsigned short*)alloc(streamEnt * 2);
        int*            csr_src   = (int*)alloc(streamEnt * 4);
        int2*           rowdeg    = (int2*)alloc((size_t)N * 8);
        int*            out_deg   = (int*)alloc((size_t)N * 4);
        int*            dstCur    = (int*)alloc(1024);
        int*            srcCur    = (int*)alloc(1024);
        unsigned short* t         = (unsigned short*)alloc((size_t)(N + 1) * FOUT * 2);  // +1 zero row
        unsigned short* hbuf      = (unsigned short*)alloc((size_t)N * FOUT * 2);
        unsigned short* Wt0       = (unsigned short*)alloc(128 * 64 * 2);
        unsigned short* Wt1       = (unsigned short*)alloc(64 * 64 * 2);
        unsigned short* Wt2       = (unsigned short*)alloc(64 * 64 * 2);

        const int nTiles = (E + TILE - 1) / TILE;   // 196

        k_setup<<<32, B, 0, stream>>>(W0, W1, W2, Wt0, Wt1, Wt2,
                                      (unsigned int*)(t + (size_t)N * FOUT),
                                      dstCur, srcCur, capP,
                                      ids, outp + (size_t)N * FOUT, 1024);
        k_binscatter<<<nTiles, 1024, 0, stream>>>(src, dst, dstCur, srcCur, dstStream, srcStream, E);
        k_csr_odeg<<<2 * NPART, 512, 0, stream>>>(dstStream, srcStream, dstCur, srcCur, capP,
                                                  rowdeg, csr_src, out_deg);

        // layer 0: 128 -> 64 (fp32 in, bf16 out)
        k_gemm_reg<128, float, unsigned short><<<gemmGrid, B, 0, stream>>>(h, out_deg, Wt0, t);
        k_spmm_b<unsigned short><<<spmmGrid, B, 0, stream>>>((const uint4*)t, rowdeg, csr_src, b0, hbuf);
        // layer 1
        k_gemm_reg<64, unsigned short, unsigned short><<<gemmGrid, B, 0, stream>>>(hbuf, out_deg, Wt1, t);
        k_spmm_b<unsigned short><<<spmmGrid, B, 0, stream>>>((const uint4*)t, rowdeg, csr_src, b1, hbuf);
        // layer 2 (fp32 final out)
        k_gemm_reg<64, unsigned short, unsigned short><<<gemmGrid, B, 0, stream>>>(hbuf, out_deg, Wt2, t);
        k_spmm_b<float><<<spmmGrid, B, 0, stream>>>((const uint4*)t, rowdeg, csr_src, b2, outp);
    } else {
        // ---------- CSR fallback (fp32, atomic build) ----------
        int*   in_deg  = (int*)alloc((size_t)N * 4);
        int*   out_deg = (int*)alloc((size_t)N * 4);
        int*   row_off = (int*)alloc((size_t)(N + 1) * 4);
        int*   cursor  = (int*)alloc((size_t)N * 4);
        int*   csr_src = (int*)alloc((size_t)E * 4);
        float* t       = (float*)alloc((size_t)N * FOUT * 4);
        float* hbuf    = (float*)alloc((size_t)N * FOUT * 4);
        int*   bsums   = (int*)alloc((size_t)SCAN_BLOCK * 4);

        const int gN = (N + B - 1) / B;
        const int gE = (E + B - 1) / B;
        const int nScanBlocks = (N + SCAN_ELEMS - 1) / SCAN_ELEMS;

        k_init_fb<<<gN, B, 0, stream>>>(in_deg, out_deg, ids, outp + (size_t)N * FOUT, N, 1024);
        k_histo<<<gE, B, 0, stream>>>(src, dst, out_deg, in_deg, E);
        k_scan_partial<<<nScanBlocks, SCAN_BLOCK, 0, stream>>>(in_deg, bsums, N);
        k_scan_blocks<<<1, SCAN_BLOCK, 0, stream>>>(bsums, nScanBlocks);
        k_scan_write<<<nScanBlocks, SCAN_BLOCK, 0, stream>>>(in_deg, bsums, row_off, cursor, N);
        k_scatter<<<gE, B, 0, stream>>>(src, dst, cursor, csr_src, E);

        k_gemm_fb<128><<<N / 32, 256, 0, stream>>>(h, out_deg, W0, t);
        k_spmm_c<<<spmmGrid, 256, 0, stream>>>(t, row_off, csr_src, b0, hbuf);
        k_gemm_fb<64><<<N / 32, 256, 0, stream>>>(hbuf, out_deg, W1, t);
        k_spmm_c<<<spmmGrid, 256, 0, stream>>>(t, row_off, csr_src, b1, hbuf);
        k_gemm_fb<64><<<N / 32, 256, 0, stream>>>(hbuf, out_deg, W2, t);
        k_spmm_c<<<spmmGrid, 256, 0, stream>>>(t, row_off, csr_src, b2, outp);
    }
}